// Round 15
// baseline (80.630 us; speedup 1.0000x reference)
//
#include <hip/hip_runtime.h>
#include <cstdint>

typedef __bf16 v8bf __attribute__((ext_vector_type(8)));
typedef float f32x4 __attribute__((ext_vector_type(4)));
typedef int i32x4 __attribute__((ext_vector_type(4)));
typedef uint16_t u16;
typedef uint32_t u32;
typedef u16 ushort8 __attribute__((ext_vector_type(8)));

__device__ __forceinline__ u16 f2bf(float f) {
  u32 u = __float_as_uint(f);
  u += 0x7FFFu + ((u >> 16) & 1u);   // round-to-nearest-even
  return (u16)(u >> 16);
}
__device__ __forceinline__ float bf2f(u16 h) {
  return __uint_as_float((u32)h << 16);
}

#define AS1(p) ((__attribute__((address_space(1))) void*)(p))

__device__ __forceinline__ v8bf ds_read_b128f(u32 addr) {
  i32x4 r;
  asm volatile("ds_read_b128 %0, %1" : "=v"(r) : "v"(addr));
  return __builtin_bit_cast(v8bf, r);
}

// Counted waits: NO clobbers; order pinned with sched_barrier(0) (rule #18).
#define WAITV(N)                                         \
  do {                                                   \
    __builtin_amdgcn_sched_barrier(0);                   \
    asm volatile("s_waitcnt vmcnt(" #N ")");             \
    __builtin_amdgcn_sched_barrier(0);                   \
  } while (0)
#define WAITL(N)                                         \
  do {                                                   \
    __builtin_amdgcn_sched_barrier(0);                   \
    asm volatile("s_waitcnt lgkmcnt(" #N ")");           \
    __builtin_amdgcn_sched_barrier(0);                   \
  } while (0)

// ---------------- K1 (fused): row norms + Y = bf16(x*rn) + Wt = bf16(x*sqrt(rn))^T ----------------
// 256 blocks (1/CU) x 32-row bands (128KB of x). Pass A: one coalesced sweep,
// PARALLEL per-row 64-lane shfl reduces (no serial lane0 loop, no atomics —
// R9's fusion failure was 0.5 blocks/CU + serial reduce). Pass B re-reads the
// band (L2-resident: 32 blocks/XCD x 128KB = 4MB = L2) via padded LDS tiles.
// Saves the separate rownorm kernel's full 32MB HBM read + one launch.
__global__ __launch_bounds__(256) void k_fused(const float* __restrict__ x,
                                               u16* __restrict__ Y,
                                               u16* __restrict__ Wt) {
  __shared__ float ps[32][5];
  __shared__ float rn[32], sq[32];
  __shared__ float tile[32][65];
  const int t = threadIdx.x;
  const int i0 = blockIdx.x * 32;
  const int wid = t >> 6, lane = t & 63;

  // Pass A: row r's 1024 floats = 256 float4s, one per thread; wave-reduce x4
  const float4* x4 = (const float4*)(x + (size_t)i0 * 1024);
#pragma unroll
  for (int r = 0; r < 32; ++r) {
    const float4 v = x4[r * 256 + t];
    float a = v.x * v.x + v.y * v.y + v.z * v.z + v.w * v.w;
#pragma unroll
    for (int off = 32; off > 0; off >>= 1) a += __shfl_down(a, off, 64);
    if (lane == 0) ps[r][wid] = a;
  }
  __syncthreads();
  if (t < 32) {
    const float s = ps[t][0] + ps[t][1] + ps[t][2] + ps[t][3];
    const float rv = 1.0f / sqrtf(s);   // norms ~32, eps clamp never binds
    rn[t] = rv;
    sq[t] = sqrtf(rv);
  }
  __syncthreads();

  // Pass B: 16 tiles of (32 i x 64 d); band re-read hits L2
  const int tr = t >> 6;         // 0..3
  const int tc = t & 63;
  for (int d0 = 0; d0 < 1024; d0 += 64) {
#pragma unroll
    for (int it = 0; it < 8; ++it) {
      const int i = it * 4 + tr;
      tile[i][tc] = x[(size_t)(i0 + i) * 1024 + d0 + tc];
    }
    __syncthreads();
    // Y[i][d] row-major: thread t -> ir = t>>3, dc = (t&7)*8  (128B/row coalesced)
    {
      const int ir = t >> 3;
      const int dc = (t & 7) * 8;
      ushort8 o;
#pragma unroll
      for (int j = 0; j < 8; ++j) o[j] = f2bf(tile[ir][dc + j] * rn[ir]);
      *(ushort8*)(Y + (size_t)(i0 + ir) * 1024 + d0 + dc) = o;
    }
    // Wt[d][i]: thread t -> dr = t>>2, ic = (t&3)*8  (64B/d-row contiguous)
    {
      const int dr = t >> 2;
      const int ic = (t & 3) * 8;
      ushort8 o;
#pragma unroll
      for (int j = 0; j < 8; ++j) o[j] = f2bf(tile[ic + j][dr] * sq[ic + j]);
      *(ushort8*)(Wt + (size_t)(d0 + dr) * 8192 + i0 + ic) = o;
    }
    __syncthreads();
  }
}

// ---------------- GEMM: C = A[M][K] * B[N][K]^T, bf16 in, f32 acc ----------------
// R8/R12-verified structure: BM=BN=128, BK=64, 4 waves (2x2), wave 64x64 = 4x4
// frags, ring-2 LDS (64KB, 2 blocks/CU), XOR-swizzle (0 conflicts), counted
// clobber-free vmcnt(8), fine ds_read/MFMA interleave with counted lgkm.
// MODE 0 (SYRK, LOWER-TRI): Z = Wt*Wt^T on the 36 lower-triangle 128^2 tiles
//   only (Z symmetric), split-K=16, xcd=b&7 owns 2 K-slices (2MB Wt band
//   L2-resident). bf16 partials -> part[zi][tl][128][128].
// MODE 1: out = sigmoid(Y*Ztb^T + Y[i][d]*zdiag[d]) — diag term from bf16 Y
//   (= x*rn), no f32 x re-read. 8 m-tiles per XCD.
template <int MODE>
__global__ __launch_bounds__(256, 2) void k_gemm128(
    const u16* __restrict__ A, const u16* __restrict__ B, void* __restrict__ Cv,
    const u16* __restrict__ Yd, const float* __restrict__ zdiag) {
  __shared__ char lds[2][32768] __attribute__((aligned(16)));
  const int tid = threadIdx.x;
  const int wave = tid >> 6;      // 0..3
  const int lane = tid & 63;
  const int wm = wave >> 1, wn = wave & 1;

  int m0, n0, k_start, K, nt;
  int zi = 0, tl = 0;
  if (MODE == 0) {
    // 576 blocks: xcd = b&7 owns K-slices {2xcd, 2xcd+1}; 36 lower-tri tiles
    const int orig = blockIdx.x;
    const int xcd = orig & 7;
    const int local = orig >> 3;            // 0..71
    const int half = (local >= 36) ? 1 : 0;
    tl = local - half * 36;                 // 0..35
    zi = xcd * 2 + half;                    // 0..15
    int tm = 0, a2 = 0;
    while (a2 + tm + 1 <= tl) { ++tm; a2 += tm; }
    const int tn = tl - a2;                 // tn <= tm
    m0 = tm * 128; n0 = tn * 128;
    k_start = zi * 512; K = 8192; nt = 8;
  } else {
    // 512 blocks: xcd = b&7 owns 8 m-tiles (2MB Y band + 2MB Ztb in L2)
    const int b = blockIdx.x;
    const int r = b >> 3;                   // 0..63
    m0 = (((b & 7) << 3) | (r >> 3)) * 128; // 64 m-tiles
    n0 = (r & 7) * 128;
    k_start = 0; K = 1024; nt = 16;
  }

  f32x4 acc[4][4] = {};

  const int frow = lane & 15;
  const u32 sw0 = (u32)(((lane >> 4) ^ (frow & 7)) << 4);  // swizzled 16B slot

  // staging: rows wave*32 + j*8 + (lane>>3), j=0..3; inverse-swizzled k-chunk
  const int srA = lane >> 3;
  const int swz8 = ((lane & 7) ^ srA) << 3;
  const u16* gA_l = A + (size_t)(m0 + wave * 32 + srA) * K + k_start + swz8;
  const u16* gB_l = B + (size_t)(n0 + wave * 32 + srA) * K + k_start + swz8;

  typedef __attribute__((address_space(3))) char* ldsp;
  ldsp l3 = (ldsp)((__attribute__((address_space(3))) void*)&lds[0][0]);
  const u32 lds0 = (u32)(uintptr_t)l3;

#define STAGE8(buf, kt)                                                        \
  do {                                                                         \
    const size_t _ko = (size_t)(kt) * 64;                                      \
    ldsp _ba = l3 + (buf) * 32768 + wave * 4096;                               \
    ldsp _bb = l3 + (buf) * 32768 + 16384 + wave * 4096;                       \
    _Pragma("unroll")                                                          \
    for (int _j = 0; _j < 4; ++_j)                                             \
      __builtin_amdgcn_global_load_lds(AS1(gA_l + _ko + (size_t)_j * 8 * K),   \
                                       (_ba + _j * 1024), 16, 0, 0);           \
    _Pragma("unroll")                                                          \
    for (int _j = 0; _j < 4; ++_j)                                             \
      __builtin_amdgcn_global_load_lds(AS1(gB_l + _ko + (size_t)_j * 8 * K),   \
                                       (_bb + _j * 1024), 16, 0, 0);           \
  } while (0)

#define MFMA4(ar, barr)                                                        \
  do {                                                                         \
    __builtin_amdgcn_s_setprio(1);                                             \
    acc[_mi][0] = __builtin_amdgcn_mfma_f32_16x16x32_bf16((ar), (barr)[0], acc[_mi][0], 0, 0, 0); \
    acc[_mi][1] = __builtin_amdgcn_mfma_f32_16x16x32_bf16((ar), (barr)[1], acc[_mi][1], 0, 0, 0); \
    acc[_mi][2] = __builtin_amdgcn_mfma_f32_16x16x32_bf16((ar), (barr)[2], acc[_mi][2], 0, 0, 0); \
    acc[_mi][3] = __builtin_amdgcn_mfma_f32_16x16x32_bf16((ar), (barr)[3], acc[_mi][3], 0, 0, 0); \
    __builtin_amdgcn_s_setprio(0);                                             \
  } while (0)

  STAGE8(0, 0);
  STAGE8(1, 1);
  for (int t = 0; t < nt; ++t) {
    const int buf = t & 1;
    if (t < nt - 1) { WAITV(8); } else { WAITV(0); }   // tile t landed; t+1 in flight
    __builtin_amdgcn_s_barrier();
    const u32 bb = lds0 + (u32)buf * 32768;
    const u32 aA = bb + (u32)((wm * 64 + frow) * 128) + sw0;
    const u32 aB = bb + 16384u + (u32)((wn * 64 + frow) * 128) + sw0;
    v8bf a0[4], a1[4], b0[4], b1[4];
    // issue order for counted lgkm (pure-DS, in-order): b0*4, a0[0], b1*4, a1[0]
    b0[0] = ds_read_b128f(aB);
    b0[1] = ds_read_b128f(aB + 2048);
    b0[2] = ds_read_b128f(aB + 4096);
    b0[3] = ds_read_b128f(aB + 6144);
    a0[0] = ds_read_b128f(aA);
    b1[0] = ds_read_b128f(aB ^ 0x40);
    b1[1] = ds_read_b128f((aB + 2048) ^ 0x40);
    b1[2] = ds_read_b128f((aB + 4096) ^ 0x40);
    b1[3] = ds_read_b128f((aB + 6144) ^ 0x40);
    a1[0] = ds_read_b128f(aA ^ 0x40);
    WAITL(5);                                   // b0*, a0[0] ready
    { const int _mi = 0; MFMA4(a0[0], b0); }
    a0[1] = ds_read_b128f(aA + 2048);
    a1[1] = ds_read_b128f((aA + 2048) ^ 0x40);
    WAITL(2);                                   // b1*, a1[0] ready
    { const int _mi = 0; MFMA4(a1[0], b1); }
    a0[2] = ds_read_b128f(aA + 4096);
    a1[2] = ds_read_b128f((aA + 4096) ^ 0x40);
    WAITL(3);                                   // a0[1] ready
    { const int _mi = 1; MFMA4(a0[1], b0); }
    a0[3] = ds_read_b128f(aA + 6144);
    a1[3] = ds_read_b128f((aA + 6144) ^ 0x40);
    WAITL(4);                                   // a1[1] ready
    { const int _mi = 1; MFMA4(a1[1], b1); }
    WAITL(3);                                   // a0[2] ready
    { const int _mi = 2; MFMA4(a0[2], b0); }
    WAITL(2);                                   // a1[2] ready
    { const int _mi = 2; MFMA4(a1[2], b1); }
    WAITL(1);                                   // a0[3] ready
    { const int _mi = 3; MFMA4(a0[3], b0); }
    WAITL(0);                                   // a1[3] ready
    { const int _mi = 3; MFMA4(a1[3], b1); }
    __builtin_amdgcn_s_barrier();               // all waves done with buf
    if (t + 2 < nt) STAGE8(buf, t + 2);         // in flight across tile t+1
  }
#undef STAGE8
#undef MFMA4

  // C/D layout (verified): col = lane&15, row = (lane>>4)*4 + reg
  const int crow = (lane >> 4) * 4;
  const int ccol = lane & 15;
#pragma unroll
  for (int mi = 0; mi < 4; ++mi) {
#pragma unroll
    for (int ni = 0; ni < 4; ++ni) {
      const int rl = wm * 64 + mi * 16 + crow;   // 0..127
      const int cl = wn * 64 + ni * 16 + ccol;   // 0..127
#pragma unroll
      for (int r = 0; r < 4; ++r) {
        float v = acc[mi][ni][r];
        if (MODE == 0) {
          // part[zi][tl][rl+r][cl] bf16
          const size_t o = (((size_t)(zi * 36 + tl)) << 14) + (size_t)(rl + r) * 128 + cl;
          ((u16*)Cv)[o] = f2bf(v);
        } else {
          const int row = m0 + rl + r;
          const int col = n0 + cl;
          const size_t o = (size_t)row * 1024 + col;
          // diag term: x[i][d]*rn[i]*zdiag[d] = Y[i][d]*zdiag[d] (Y bf16 exact-enough)
          float z = v + bf2f(Yd[o]) * zdiag[col];
          ((float*)Cv)[o] = 1.0f / (1.0f + __expf(-z));
        }
      }
    }
  }
}

// ---------------- K4: reduce 16 bf16 partials over lower-tri tiles -> full Ztb ----------------
// Each block: one 16-row slab of one lower tile. Sums 16 partials -> Ztb[m][n];
// off-diag tiles also write mirrored Ztb[n][m] via LDS transpose (Z symmetric).
// Diag elements -> zdiag (f32), zeroed in Ztb.
__global__ __launch_bounds__(256) void k_reduce2(const u16* __restrict__ part,
                                                 u16* __restrict__ Ztb,
                                                 float* __restrict__ zdiag) {
  __shared__ u16 t16[16][128];
  const int tile = blockIdx.x >> 3;
  const int slab = blockIdx.x & 7;
  int tm = 0, a2 = 0;
  while (a2 + tm + 1 <= tile) { ++tm; a2 += tm; }
  const int tn = tile - a2;

  const int rl = slab * 16 + (threadIdx.x >> 4);   // 0..127 row in tile
  const int cl0 = (threadIdx.x & 15) * 8;          // col start
  const size_t eo = (size_t)tile * 16384 + (size_t)rl * 128 + cl0;

  float s[8] = {0, 0, 0, 0, 0, 0, 0, 0};
#pragma unroll
  for (int p = 0; p < 16; ++p) {
    ushort8 pk = *(const ushort8*)(part + (size_t)p * (36 * 16384) + eo);
#pragma unroll
    for (int j = 0; j < 8; ++j) s[j] += bf2f(pk[j]);
  }
  const int m = tm * 128 + rl;
  ushort8 o;
#pragma unroll
  for (int j = 0; j < 8; ++j) {
    const int n = tn * 128 + cl0 + j;
    if (m == n) { zdiag[m] = s[j]; o[j] = 0; }
    else o[j] = f2bf(s[j]);
  }
  *(ushort8*)(Ztb + (size_t)m * 1024 + tn * 128 + cl0) = o;

  if (tm != tn) {
    *(ushort8*)(&t16[threadIdx.x >> 4][cl0]) = o;
    __syncthreads();
    // mirror: Ztb[tn*128 + c][tm*128 + slab*16 + k] = t16[k][c]
    const int c = threadIdx.x >> 1;
    const int kh = (threadIdx.x & 1) * 8;
    ushort8 g;
#pragma unroll
    for (int j = 0; j < 8; ++j) g[j] = t16[kh + j][c];
    *(ushort8*)(Ztb + (size_t)(tn * 128 + c) * 1024 + tm * 128 + slab * 16 + kh) = g;
  }
}

extern "C" void kernel_launch(void* const* d_in, const int* in_sizes, int n_in,
                              void* d_out, int out_size, void* d_ws, size_t ws_size,
                              hipStream_t stream) {
  const float* x = (const float*)d_in[0];
  float* out = (float*)d_out;
  char* ws = (char*)d_ws;

  // ws layout (~34.1 MB): (unused 64KB) | Y | Wt | Ztb | zdiag
  u16* Y    = (u16*)(ws + (1u << 16));                         // 16 MB
  u16* Wt   = (u16*)(ws + (1u << 16) + (16u << 20));           // 16 MB
  u16* Ztb  = (u16*)(ws + (1u << 16) + (32u << 20));           // 2 MB
  float* zdiag = (float*)(ws + (1u << 16) + (34u << 20));      // 4 KB
  u16* part = (u16*)d_out;  // 16 slices x 36-tile bf16 partials (18.9 MB of 32 MB)

  // fused rownorm+build: 256 blocks x 32-row bands
  k_fused<<<256, 256, 0, stream>>>(x, Y, Wt);
  // Z lower-tri: 36 tiles (128^2) x 16 K-slices = 576 blocks
  k_gemm128<0><<<576, 256, 0, stream>>>(Wt, Wt, part, nullptr, nullptr);
  k_reduce2<<<288, 256, 0, stream>>>(part, Ztb, zdiag);
  // out[i][d] = sigmoid( sum_k Y[i][k]*Ztb[d][k] + Y[i][d]*zdiag[d] ): 512 blocks
  k_gemm128<1><<<512, 256, 0, stream>>>(Y, Ztb, out, Y, zdiag);
}

// Round 16
// 70.639 us; speedup vs baseline: 1.1414x; 1.1414x over previous
//
#include <hip/hip_runtime.h>
#include <cstdint>

typedef __bf16 v8bf __attribute__((ext_vector_type(8)));
typedef float f32x4 __attribute__((ext_vector_type(4)));
typedef int i32x4 __attribute__((ext_vector_type(4)));
typedef uint16_t u16;
typedef uint32_t u32;
typedef u16 ushort8 __attribute__((ext_vector_type(8)));

__device__ __forceinline__ u16 f2bf(float f) {
  u32 u = __float_as_uint(f);
  u += 0x7FFFu + ((u >> 16) & 1u);   // round-to-nearest-even
  return (u16)(u >> 16);
}
__device__ __forceinline__ float bf2f(u16 h) {
  return __uint_as_float((u32)h << 16);
}

#define AS1(p) ((__attribute__((address_space(1))) void*)(p))

__device__ __forceinline__ v8bf ds_read_b128f(u32 addr) {
  i32x4 r;
  asm volatile("ds_read_b128 %0, %1" : "=v"(r) : "v"(addr));
  return __builtin_bit_cast(v8bf, r);
}

// Counted waits: NO clobbers; order pinned with sched_barrier(0) (rule #18).
#define WAITV(N)                                         \
  do {                                                   \
    __builtin_amdgcn_sched_barrier(0);                   \
    asm volatile("s_waitcnt vmcnt(" #N ")");             \
    __builtin_amdgcn_sched_barrier(0);                   \
  } while (0)
#define WAITL(N)                                         \
  do {                                                   \
    __builtin_amdgcn_sched_barrier(0);                   \
    asm volatile("s_waitcnt lgkmcnt(" #N ")");           \
    __builtin_amdgcn_sched_barrier(0);                   \
  } while (0)

// ---------------- K1: 1/||x_row|| ----------------
__global__ __launch_bounds__(256) void k_rownorm(const float* __restrict__ x,
                                                 float* __restrict__ rnorm) {
  const int row = blockIdx.x;
  const float4 v = ((const float4*)(x + (size_t)row * 1024))[threadIdx.x];
  float s = v.x * v.x + v.y * v.y + v.z * v.z + v.w * v.w;
#pragma unroll
  for (int off = 32; off > 0; off >>= 1) s += __shfl_down(s, off, 64);
  __shared__ float ps[4];
  if ((threadIdx.x & 63) == 0) ps[threadIdx.x >> 6] = s;
  __syncthreads();
  if (threadIdx.x == 0) {
    float t = ps[0] + ps[1] + ps[2] + ps[3];
    rnorm[row] = 1.0f / sqrtf(t);  // norms ~32, eps clamp never binds
  }
}

// ---------------- K2: build Y = bf16(x*rn) [8192][1024], Wt = bf16(x*sqrt(rn))^T [1024][8192] ----------------
// Z = W^T W (SYRK form): Z[d][e] = sum_i x_id*x_ie*rn_i.
__global__ __launch_bounds__(256) void k_build(const float* __restrict__ x,
                                               const float* __restrict__ rnorm,
                                               u16* __restrict__ Y,
                                               u16* __restrict__ Wt) {
  __shared__ float tile[64][65];
  __shared__ float rn[64], sq[64];
  const int d0 = blockIdx.x * 64;   // 0..1023
  const int i0 = blockIdx.y * 64;   // 0..8191
  const int tr = threadIdx.x >> 6;  // 0..3
  const int tc = threadIdx.x & 63;
#pragma unroll
  for (int it = 0; it < 16; ++it) {
    int r = it * 4 + tr;
    tile[r][tc] = x[(size_t)(i0 + r) * 1024 + d0 + tc];
  }
  if (threadIdx.x < 64) {
    float rv = rnorm[i0 + threadIdx.x];
    rn[threadIdx.x] = rv;
    sq[threadIdx.x] = sqrtf(rv);
  }
  __syncthreads();
#pragma unroll
  for (int it = 0; it < 16; ++it) {
    int r = it * 4 + tr;
    Y[(size_t)(i0 + r) * 1024 + d0 + tc] = f2bf(tile[r][tc] * rn[r]);
  }
#pragma unroll
  for (int it = 0; it < 16; ++it) {
    int rr = it * 4 + tr;            // d within tile
    Wt[(size_t)(d0 + rr) * 8192 + i0 + tc] = f2bf(tile[tc][rr] * sq[tc]);
  }
}

// ---------------- GEMM: C = A[M][K] * B[N][K]^T, bf16 in, f32 acc ----------------
// R8/R12-verified structure: BM=BN=128, BK=64, 4 waves (2x2), wave 64x64 = 4x4
// frags, ring-2 LDS (64KB, 2 blocks/CU), XOR-swizzle (0 conflicts), counted
// clobber-free vmcnt(8), fine ds_read/MFMA interleave with counted lgkm.
// MODE 0 (SYRK, LOWER-TRI): Z = Wt*Wt^T on the 36 lower-triangle 128^2 tiles
//   only (Z symmetric), split-K=16, xcd=b&7 owns 2 K-slices (2MB Wt band
//   L2-resident). bf16 partials -> part[zi][tl][128][128].
// MODE 1: out = sigmoid(Y*Ztb^T + Y[i][d]*zdiag[d]) — diag term from bf16 Y
//   (= x*rn), no f32 x re-read. 8 m-tiles per XCD.
template <int MODE>
__global__ __launch_bounds__(256, 2) void k_gemm128(
    const u16* __restrict__ A, const u16* __restrict__ B, void* __restrict__ Cv,
    const u16* __restrict__ Yd, const float* __restrict__ zdiag) {
  __shared__ char lds[2][32768] __attribute__((aligned(16)));
  const int tid = threadIdx.x;
  const int wave = tid >> 6;      // 0..3
  const int lane = tid & 63;
  const int wm = wave >> 1, wn = wave & 1;

  int m0, n0, k_start, K, nt;
  int zi = 0, tl = 0;
  if (MODE == 0) {
    // 576 blocks: xcd = b&7 owns K-slices {2xcd, 2xcd+1}; 36 lower-tri tiles
    const int orig = blockIdx.x;
    const int xcd = orig & 7;
    const int local = orig >> 3;            // 0..71
    const int half = (local >= 36) ? 1 : 0;
    tl = local - half * 36;                 // 0..35
    zi = xcd * 2 + half;                    // 0..15
    int tm = 0, a2 = 0;
    while (a2 + tm + 1 <= tl) { ++tm; a2 += tm; }
    const int tn = tl - a2;                 // tn <= tm
    m0 = tm * 128; n0 = tn * 128;
    k_start = zi * 512; K = 8192; nt = 8;
  } else {
    // 512 blocks: xcd = b&7 owns 8 m-tiles (2MB Y band + 2MB Ztb in L2)
    const int b = blockIdx.x;
    const int r = b >> 3;                   // 0..63
    m0 = (((b & 7) << 3) | (r >> 3)) * 128; // 64 m-tiles
    n0 = (r & 7) * 128;
    k_start = 0; K = 1024; nt = 16;
  }

  f32x4 acc[4][4] = {};

  const int frow = lane & 15;
  const u32 sw0 = (u32)(((lane >> 4) ^ (frow & 7)) << 4);  // swizzled 16B slot

  // staging: rows wave*32 + j*8 + (lane>>3), j=0..3; inverse-swizzled k-chunk
  const int srA = lane >> 3;
  const int swz8 = ((lane & 7) ^ srA) << 3;
  const u16* gA_l = A + (size_t)(m0 + wave * 32 + srA) * K + k_start + swz8;
  const u16* gB_l = B + (size_t)(n0 + wave * 32 + srA) * K + k_start + swz8;

  typedef __attribute__((address_space(3))) char* ldsp;
  ldsp l3 = (ldsp)((__attribute__((address_space(3))) void*)&lds[0][0]);
  const u32 lds0 = (u32)(uintptr_t)l3;

#define STAGE8(buf, kt)                                                        \
  do {                                                                         \
    const size_t _ko = (size_t)(kt) * 64;                                      \
    ldsp _ba = l3 + (buf) * 32768 + wave * 4096;                               \
    ldsp _bb = l3 + (buf) * 32768 + 16384 + wave * 4096;                       \
    _Pragma("unroll")                                                          \
    for (int _j = 0; _j < 4; ++_j)                                             \
      __builtin_amdgcn_global_load_lds(AS1(gA_l + _ko + (size_t)_j * 8 * K),   \
                                       (_ba + _j * 1024), 16, 0, 0);           \
    _Pragma("unroll")                                                          \
    for (int _j = 0; _j < 4; ++_j)                                             \
      __builtin_amdgcn_global_load_lds(AS1(gB_l + _ko + (size_t)_j * 8 * K),   \
                                       (_bb + _j * 1024), 16, 0, 0);           \
  } while (0)

#define MFMA4(ar, barr)                                                        \
  do {                                                                         \
    __builtin_amdgcn_s_setprio(1);                                             \
    acc[_mi][0] = __builtin_amdgcn_mfma_f32_16x16x32_bf16((ar), (barr)[0], acc[_mi][0], 0, 0, 0); \
    acc[_mi][1] = __builtin_amdgcn_mfma_f32_16x16x32_bf16((ar), (barr)[1], acc[_mi][1], 0, 0, 0); \
    acc[_mi][2] = __builtin_amdgcn_mfma_f32_16x16x32_bf16((ar), (barr)[2], acc[_mi][2], 0, 0, 0); \
    acc[_mi][3] = __builtin_amdgcn_mfma_f32_16x16x32_bf16((ar), (barr)[3], acc[_mi][3], 0, 0, 0); \
    __builtin_amdgcn_s_setprio(0);                                             \
  } while (0)

  STAGE8(0, 0);
  STAGE8(1, 1);
  for (int t = 0; t < nt; ++t) {
    const int buf = t & 1;
    if (t < nt - 1) { WAITV(8); } else { WAITV(0); }   // tile t landed; t+1 in flight
    __builtin_amdgcn_s_barrier();
    const u32 bb = lds0 + (u32)buf * 32768;
    const u32 aA = bb + (u32)((wm * 64 + frow) * 128) + sw0;
    const u32 aB = bb + 16384u + (u32)((wn * 64 + frow) * 128) + sw0;
    v8bf a0[4], a1[4], b0[4], b1[4];
    // issue order for counted lgkm (pure-DS, in-order): b0*4, a0[0], b1*4, a1[0]
    b0[0] = ds_read_b128f(aB);
    b0[1] = ds_read_b128f(aB + 2048);
    b0[2] = ds_read_b128f(aB + 4096);
    b0[3] = ds_read_b128f(aB + 6144);
    a0[0] = ds_read_b128f(aA);
    b1[0] = ds_read_b128f(aB ^ 0x40);
    b1[1] = ds_read_b128f((aB + 2048) ^ 0x40);
    b1[2] = ds_read_b128f((aB + 4096) ^ 0x40);
    b1[3] = ds_read_b128f((aB + 6144) ^ 0x40);
    a1[0] = ds_read_b128f(aA ^ 0x40);
    WAITL(5);                                   // b0*, a0[0] ready
    { const int _mi = 0; MFMA4(a0[0], b0); }
    a0[1] = ds_read_b128f(aA + 2048);
    a1[1] = ds_read_b128f((aA + 2048) ^ 0x40);
    WAITL(2);                                   // b1*, a1[0] ready
    { const int _mi = 0; MFMA4(a1[0], b1); }
    a0[2] = ds_read_b128f(aA + 4096);
    a1[2] = ds_read_b128f((aA + 4096) ^ 0x40);
    WAITL(3);                                   // a0[1] ready
    { const int _mi = 1; MFMA4(a0[1], b0); }
    a0[3] = ds_read_b128f(aA + 6144);
    a1[3] = ds_read_b128f((aA + 6144) ^ 0x40);
    WAITL(4);                                   // a1[1] ready
    { const int _mi = 1; MFMA4(a1[1], b1); }
    WAITL(3);                                   // a0[2] ready
    { const int _mi = 2; MFMA4(a0[2], b0); }
    WAITL(2);                                   // a1[2] ready
    { const int _mi = 2; MFMA4(a1[2], b1); }
    WAITL(1);                                   // a0[3] ready
    { const int _mi = 3; MFMA4(a0[3], b0); }
    WAITL(0);                                   // a1[3] ready
    { const int _mi = 3; MFMA4(a1[3], b1); }
    __builtin_amdgcn_s_barrier();               // all waves done with buf
    if (t + 2 < nt) STAGE8(buf, t + 2);         // in flight across tile t+1
  }
#undef STAGE8
#undef MFMA4

  // C/D layout (verified): col = lane&15, row = (lane>>4)*4 + reg
  const int crow = (lane >> 4) * 4;
  const int ccol = lane & 15;
#pragma unroll
  for (int mi = 0; mi < 4; ++mi) {
#pragma unroll
    for (int ni = 0; ni < 4; ++ni) {
      const int rl = wm * 64 + mi * 16 + crow;   // 0..127
      const int cl = wn * 64 + ni * 16 + ccol;   // 0..127
#pragma unroll
      for (int r = 0; r < 4; ++r) {
        float v = acc[mi][ni][r];
        if (MODE == 0) {
          // part[zi][tl][rl+r][cl] bf16
          const size_t o = (((size_t)(zi * 36 + tl)) << 14) + (size_t)(rl + r) * 128 + cl;
          ((u16*)Cv)[o] = f2bf(v);
        } else {
          const int row = m0 + rl + r;
          const int col = n0 + cl;
          const size_t o = (size_t)row * 1024 + col;
          // diag term: x[i][d]*rn[i]*zdiag[d] = Y[i][d]*zdiag[d] (Y bf16 exact-enough)
          float z = v + bf2f(Yd[o]) * zdiag[col];
          ((float*)Cv)[o] = 1.0f / (1.0f + __expf(-z));
        }
      }
    }
  }
}

// ---------------- K4: reduce 16 bf16 partials over lower-tri tiles -> full Ztb ----------------
// Each block: one 16-row slab of one lower tile. Sums 16 partials -> Ztb[m][n];
// off-diag tiles also write mirrored Ztb[n][m] via LDS transpose (Z symmetric).
// Diag elements -> zdiag (f32), zeroed in Ztb.
__global__ __launch_bounds__(256) void k_reduce2(const u16* __restrict__ part,
                                                 u16* __restrict__ Ztb,
                                                 float* __restrict__ zdiag) {
  __shared__ u16 t16[16][128];
  const int tile = blockIdx.x >> 3;
  const int slab = blockIdx.x & 7;
  int tm = 0, a2 = 0;
  while (a2 + tm + 1 <= tile) { ++tm; a2 += tm; }
  const int tn = tile - a2;

  const int rl = slab * 16 + (threadIdx.x >> 4);   // 0..127 row in tile
  const int cl0 = (threadIdx.x & 15) * 8;          // col start
  const size_t eo = (size_t)tile * 16384 + (size_t)rl * 128 + cl0;

  float s[8] = {0, 0, 0, 0, 0, 0, 0, 0};
#pragma unroll
  for (int p = 0; p < 16; ++p) {
    ushort8 pk = *(const ushort8*)(part + (size_t)p * (36 * 16384) + eo);
#pragma unroll
    for (int j = 0; j < 8; ++j) s[j] += bf2f(pk[j]);
  }
  const int m = tm * 128 + rl;
  ushort8 o;
#pragma unroll
  for (int j = 0; j < 8; ++j) {
    const int n = tn * 128 + cl0 + j;
    if (m == n) { zdiag[m] = s[j]; o[j] = 0; }
    else o[j] = f2bf(s[j]);
  }
  *(ushort8*)(Ztb + (size_t)m * 1024 + tn * 128 + cl0) = o;

  if (tm != tn) {
    *(ushort8*)(&t16[threadIdx.x >> 4][cl0]) = o;
    __syncthreads();
    // mirror: Ztb[tn*128 + c][tm*128 + slab*16 + k] = t16[k][c]
    const int c = threadIdx.x >> 1;
    const int kh = (threadIdx.x & 1) * 8;
    ushort8 g;
#pragma unroll
    for (int j = 0; j < 8; ++j) g[j] = t16[kh + j][c];
    *(ushort8*)(Ztb + (size_t)(tn * 128 + c) * 1024 + tm * 128 + slab * 16 + kh) = g;
  }
}

extern "C" void kernel_launch(void* const* d_in, const int* in_sizes, int n_in,
                              void* d_out, int out_size, void* d_ws, size_t ws_size,
                              hipStream_t stream) {
  const float* x = (const float*)d_in[0];
  float* out = (float*)d_out;
  char* ws = (char*)d_ws;

  // ws layout (~34.1 MB): rnorm | Y | Wt | Ztb | zdiag
  float* rnorm = (float*)ws;                                   // 32 KB
  u16* Y    = (u16*)(ws + (1u << 16));                         // 16 MB
  u16* Wt   = (u16*)(ws + (1u << 16) + (16u << 20));           // 16 MB
  u16* Ztb  = (u16*)(ws + (1u << 16) + (32u << 20));           // 2 MB
  float* zdiag = (float*)(ws + (1u << 16) + (34u << 20));      // 4 KB
  u16* part = (u16*)d_out;  // 16 slices x 36-tile bf16 partials (18.9 MB of 32 MB)

  k_rownorm<<<8192, 256, 0, stream>>>(x, rnorm);
  k_build<<<dim3(16, 128), 256, 0, stream>>>(x, rnorm, Y, Wt);
  // Z lower-tri: 36 tiles (128^2) x 16 K-slices = 576 blocks
  k_gemm128<0><<<576, 256, 0, stream>>>(Wt, Wt, part, nullptr, nullptr);
  k_reduce2<<<288, 256, 0, stream>>>(part, Ztb, zdiag);
  // out[i][d] = sigmoid( sum_k Y[i][k]*Ztb[d][k] + Y[i][d]*zdiag[d] ): 512 blocks
  k_gemm128<1><<<512, 256, 0, stream>>>(Y, Ztb, out, Y, zdiag);
}